// Round 12
// baseline (7038.443 us; speedup 1.0000x reference)
//
#include <hip/hip_runtime.h>
#include <hip/hip_bf16.h>
#include <hip/hip_fp16.h>

// LiquidLinear: xin = x@Wi^T + bi ; scan: h' = (1-sig(tau))h + sig(tau)tanh(xin_t + h@Wr^T + br)
// outs = hs@Wo^T + bo ; outputs = [outs (B,S,DOUT) fp32][h_final (B,H) fp32]
// B=64 S=1024 DIN=H=DOUT=512
//
// R12: exchange-free scan (R9 structure) with the weight fragments as 46
// INDIVIDUALLY NAMED variables (no arrays). R9-R11 produced byte-identical
// binaries at VGPR_Count=128 across THREE different occupancy declarations --
// proof the occupancy/budget knobs were irrelevant: the f16x8 wv*[N] ARRAYS
// were lowered to scratch before register allocation (rule #20 aggregate trap),
// and every step reloaded ~736B/thread from L2-backed scratch (~3us/step).
// Named scalars + hand-unrolled macros remove the aggregate; waves_per_eu(2,2)
// gives the 256-VGPR budget the ~250-reg working set needs.

typedef _Float16 f16x8 __attribute__((ext_vector_type(8)));
typedef float f32x4 __attribute__((ext_vector_type(4)));
typedef float floatv4 __attribute__((ext_vector_type(4)));
typedef unsigned short ushort4v __attribute__((ext_vector_type(4)));
typedef unsigned int uint4v __attribute__((ext_vector_type(4)));

#define NSTEP 1024

__device__ __forceinline__ unsigned short f2h(float f) {
    _Float16 h = (_Float16)f;
    return *(unsigned short*)&h;
}
__device__ __forceinline__ float tanh_fast(float x) {
    float e = __expf(2.f * x);
    return 1.f - 2.f / (e + 1.f);
}

// ---------------------------------------------------------------- GEMM1: xin = x @ Wi^T + bi
__global__ __launch_bounds__(256) void gemm_xin(
    const float* __restrict__ X, const float* __restrict__ Wi,
    const float* __restrict__ bi, float* __restrict__ xin)
{
    __shared__ unsigned short As[128][40];
    __shared__ unsigned short Bs[128][40];
    const int bm = blockIdx.x, bn = blockIdx.y;
    const int tid = threadIdx.x, w = tid >> 6, l = tid & 63;
    const int wm = w >> 1, wn = w & 1;
    f32x4 acc[4][4] = {};

    for (int kt = 0; kt < 512; kt += 32) {
        __syncthreads();
        #pragma unroll
        for (int j = 0; j < 4; j++) {
            int q = tid + 256 * j;
            int row = q >> 3, c4 = (q & 7) * 4;
            floatv4 va = *(const floatv4*)&X[(size_t)(bm * 128 + row) * 512 + kt + c4];
            floatv4 vb = *(const floatv4*)&Wi[(size_t)(bn * 128 + row) * 512 + kt + c4];
            ushort4v pa, pb;
            #pragma unroll
            for (int e = 0; e < 4; e++) { pa[e] = f2h(va[e]); pb[e] = f2h(vb[e]); }
            *(ushort4v*)&As[row][c4] = pa;
            *(ushort4v*)&Bs[row][c4] = pb;
        }
        __syncthreads();
        f16x8 a[4], b[4];
        #pragma unroll
        for (int i = 0; i < 4; i++)
            a[i] = *(const f16x8*)&As[wm * 64 + i * 16 + (l & 15)][(l >> 4) * 8];
        #pragma unroll
        for (int i = 0; i < 4; i++)
            b[i] = *(const f16x8*)&Bs[wn * 64 + i * 16 + (l & 15)][(l >> 4) * 8];
        #pragma unroll
        for (int i = 0; i < 4; i++)
            #pragma unroll
            for (int j = 0; j < 4; j++)
                acc[i][j] = __builtin_amdgcn_mfma_f32_16x16x32_f16(a[i], b[j], acc[i][j], 0, 0, 0);
    }
    #pragma unroll
    for (int i = 0; i < 4; i++)
        #pragma unroll
        for (int j = 0; j < 4; j++)
            #pragma unroll
            for (int r = 0; r < 4; r++) {
                int m = bm * 128 + wm * 64 + i * 16 + (l >> 4) * 4 + r;
                int n = bn * 128 + wn * 64 + j * 16 + (l & 15);
                int bb = m >> 10, tt = m & 1023;
                xin[((size_t)tt * 64 + bb) * 512 + n] = acc[i][j][r] + bi[n];
            }
}

// ---------------------------------------------------------------- GEMM3: outs = hs @ Wo^T + bo
__global__ __launch_bounds__(256) void gemm_out(
    const unsigned short* __restrict__ hs, const float* __restrict__ Wo,
    const float* __restrict__ bo, float* __restrict__ out)
{
    __shared__ unsigned short As[128][40];
    __shared__ unsigned short Bs[128][40];
    const int bm = blockIdx.x, bn = blockIdx.y;
    const int tid = threadIdx.x, w = tid >> 6, l = tid & 63;
    const int wm = w >> 1, wn = w & 1;
    f32x4 acc[4][4] = {};

    for (int kt = 0; kt < 512; kt += 32) {
        __syncthreads();
        #pragma unroll
        for (int j = 0; j < 2; j++) {
            int q = tid + 256 * j;
            int row = q >> 2, c8 = (q & 3) * 8;
            int r = bm * 128 + row;
            int ra = (r & 1023) * 64 + (r >> 10);
            f16x8 v = *(const f16x8*)&hs[(size_t)ra * 512 + kt + c8];
            *(f16x8*)&As[row][c8] = v;
        }
        #pragma unroll
        for (int j = 0; j < 4; j++) {
            int q = tid + 256 * j;
            int row = q >> 3, c4 = (q & 7) * 4;
            floatv4 vb = *(const floatv4*)&Wo[(size_t)(bn * 128 + row) * 512 + kt + c4];
            ushort4v pb;
            #pragma unroll
            for (int e = 0; e < 4; e++) pb[e] = f2h(vb[e]);
            *(ushort4v*)&Bs[row][c4] = pb;
        }
        __syncthreads();
        f16x8 a[4], b[4];
        #pragma unroll
        for (int i = 0; i < 4; i++)
            a[i] = *(const f16x8*)&As[wm * 64 + i * 16 + (l & 15)][(l >> 4) * 8];
        #pragma unroll
        for (int i = 0; i < 4; i++)
            b[i] = *(const f16x8*)&Bs[wn * 64 + i * 16 + (l & 15)][(l >> 4) * 8];
        #pragma unroll
        for (int i = 0; i < 4; i++)
            #pragma unroll
            for (int j = 0; j < 4; j++)
                acc[i][j] = __builtin_amdgcn_mfma_f32_16x16x32_f16(a[i], b[j], acc[i][j], 0, 0, 0);
    }
    #pragma unroll
    for (int i = 0; i < 4; i++)
        #pragma unroll
        for (int j = 0; j < 4; j++)
            #pragma unroll
            for (int r = 0; r < 4; r++) {
                int m = bm * 128 + wm * 64 + i * 16 + (l >> 4) * 4 + r;
                int n = bn * 128 + wn * 64 + j * 16 + (l & 15);
                out[(size_t)m * 512 + n] = acc[i][j][r] + bo[n];
            }
}

// ---------------------------------------------------------------- scan (exchange-free, named frags)
// 4 blocks; block g owns batches [g*16,+16). Wave w owns n-cols [w*64,+64):
// tiles 0,1 (kt 0..15) + tile 2 (kt 0..13) in NAMED VGPR frags (46 x 4 = 184 regs);
// tile 2 kt14,15 (chunks 16,17) + tile 3 kt0..15 (chunks 0..15) in LDS (18 KB/wave).
// h: [16][512] fp16 LDS, XOR-swizzled (byte ^= (row&7)<<4).
#define LDW(DST, TILE, KT) do {                                                          \
    const float* p_ = &Wr[(size_t)(w * 64 + (TILE) * 16 + (l & 15)) * 512               \
                          + (KT) * 32 + (l >> 4) * 8];                                   \
    floatv4 u0_ = *(const floatv4*)p_;                                                   \
    floatv4 u1_ = *(const floatv4*)(p_ + 4);                                             \
    f16x8 f_;                                                                            \
    f_[0] = (_Float16)u0_[0]; f_[1] = (_Float16)u0_[1];                                  \
    f_[2] = (_Float16)u0_[2]; f_[3] = (_Float16)u0_[3];                                  \
    f_[4] = (_Float16)u1_[0]; f_[5] = (_Float16)u1_[1];                                  \
    f_[6] = (_Float16)u1_[2]; f_[7] = (_Float16)u1_[3];                                  \
    DST = f_;                                                                            \
} while (0)

#define DECLW(NAME, TILE, KT) f16x8 NAME; LDW(NAME, TILE, KT)

#define AH(KT) (*(const f16x8*)((const char*)h16 +                                       \
    ((((l & 15) * 1024) + (KT) * 64 + ((l >> 4) * 16)) ^ ((l & 7) << 4))))

#define BL(CH) (*(const f16x8*)&wlds[(w * 18 + (CH)) * 512 + l * 8])

#define MF(A, B, C) C = __builtin_amdgcn_mfma_f32_16x16x32_f16(A, B, C, 0, 0, 0)

#define KSTEP_V(KT, B0, B1, B2) do {                                                     \
    f16x8 ah_ = AH(KT);                                                                  \
    MF(ah_, B0, acc0); MF(ah_, B1, acc1); MF(ah_, B2, acc2); MF(ah_, BL(KT), acc3);      \
} while (0)

#define KSTEP_L(KT, B0, B1, CH2) do {                                                    \
    f16x8 ah_ = AH(KT);                                                                  \
    MF(ah_, B0, acc0); MF(ah_, B1, acc1); MF(ah_, BL(CH2), acc2); MF(ah_, BL(KT), acc3); \
} while (0)

#define LDXV(XV, TILE) do {                                                              \
    const float* q_ = &xin[((size_t)t * 64 + g * 16 + mr4) * 512                         \
                           + w * 64 + (TILE) * 16 + (l & 15)];                           \
    XV[0] = q_[0]; XV[1] = q_[512]; XV[2] = q_[1024]; XV[3] = q_[1536];                  \
} while (0)

#define UPD(TILE, ACC, XV) do {                                                          \
    _Float16 h0_, h1_, h2_, h3_;                                                         \
    *(unsigned short*)&h0_ = (unsigned short)(hpk[TILE][0] & 0xffff);                    \
    *(unsigned short*)&h1_ = (unsigned short)(hpk[TILE][0] >> 16);                       \
    *(unsigned short*)&h2_ = (unsigned short)(hpk[TILE][1] & 0xffff);                    \
    *(unsigned short*)&h3_ = (unsigned short)(hpk[TILE][1] >> 16);                       \
    float n0_ = dc[TILE] * (float)h0_ + dd[TILE] * tanh_fast(ACC[0] + XV[0] + bb[TILE]); \
    float n1_ = dc[TILE] * (float)h1_ + dd[TILE] * tanh_fast(ACC[1] + XV[1] + bb[TILE]); \
    float n2_ = dc[TILE] * (float)h2_ + dd[TILE] * tanh_fast(ACC[2] + XV[2] + bb[TILE]); \
    float n3_ = dc[TILE] * (float)h3_ + dd[TILE] * tanh_fast(ACC[3] + XV[3] + bb[TILE]); \
    unsigned short q0_ = f2h(n0_), q1_ = f2h(n1_), q2_ = f2h(n2_), q3_ = f2h(n3_);       \
    hpk[TILE][0] = (unsigned)q0_ | ((unsigned)q1_ << 16);                                \
    hpk[TILE][1] = (unsigned)q2_ | ((unsigned)q3_ << 16);                                \
    int col_ = w * 64 + (TILE) * 16 + (l & 15);                                          \
    int b0_ = ((mr4 + 0) * 1024 + col_ * 2) ^ (((mr4 + 0) & 7) << 4);                    \
    int b1_ = ((mr4 + 1) * 1024 + col_ * 2) ^ (((mr4 + 1) & 7) << 4);                    \
    int b2_ = ((mr4 + 2) * 1024 + col_ * 2) ^ (((mr4 + 2) & 7) << 4);                    \
    int b3_ = ((mr4 + 3) * 1024 + col_ * 2) ^ (((mr4 + 3) & 7) << 4);                    \
    *(unsigned short*)((char*)h16 + b0_) = q0_;                                          \
    *(unsigned short*)((char*)h16 + b1_) = q1_;                                          \
    *(unsigned short*)((char*)h16 + b2_) = q2_;                                          \
    *(unsigned short*)((char*)h16 + b3_) = q3_;                                          \
    size_t hr_ = ((size_t)t * 64 + g * 16 + mr4) * 512 + col_;                           \
    hs[hr_] = q0_; hs[hr_ + 512] = q1_; hs[hr_ + 1024] = q2_; hs[hr_ + 1536] = q3_;      \
} while (0)

__global__ __attribute__((amdgpu_flat_work_group_size(512, 512), amdgpu_waves_per_eu(2, 2)))
void scan_g(
    const float* __restrict__ Wr, const float* __restrict__ brv,
    const float* __restrict__ tau, const float* __restrict__ xin,
    unsigned short* __restrict__ hs, float* __restrict__ hfinal)
{
    const int g = blockIdx.x;
    const int tid = threadIdx.x, w = tid >> 6, l = tid & 63;

    __shared__ unsigned short wlds[73728];   // 144KB: 8 waves x 18 chunks x 512 ushort
    __shared__ unsigned short h16[8192];     // 16KB: h fp16 [16][512], XOR-swizzled

    ((uint4v*)h16)[tid] = uint4v{0, 0, 0, 0};
    ((uint4v*)h16)[tid + 512] = uint4v{0, 0, 0, 0};

    // ---- LDS-resident weights: tile 3 (chunks 0..15), tile 2 kt14,15 (chunks 16,17)
    #pragma unroll
    for (int kt = 0; kt < 16; kt++) {
        const float* p = &Wr[(size_t)(w * 64 + 3 * 16 + (l & 15)) * 512 + kt * 32 + (l >> 4) * 8];
        f16x8 f;
        #pragma unroll
        for (int e = 0; e < 8; e++) f[e] = (_Float16)p[e];
        *(f16x8*)&wlds[(w * 18 + kt) * 512 + l * 8] = f;
    }
    #pragma unroll
    for (int kt = 14; kt < 16; kt++) {
        const float* p = &Wr[(size_t)(w * 64 + 2 * 16 + (l & 15)) * 512 + kt * 32 + (l >> 4) * 8];
        f16x8 f;
        #pragma unroll
        for (int e = 0; e < 8; e++) f[e] = (_Float16)p[e];
        *(f16x8*)&wlds[(w * 18 + 16 + (kt - 14)) * 512 + l * 8] = f;
    }

    // ---- 46 named VGPR weight fragments (NO arrays -> no scratch lowering)
    DECLW(W0a, 0, 0);  DECLW(W0b, 0, 1);  DECLW(W0c, 0, 2);  DECLW(W0d, 0, 3);
    DECLW(W0e, 0, 4);  DECLW(W0f, 0, 5);  DECLW(W0g, 0, 6);  DECLW(W0h, 0, 7);
    DECLW(W0i, 0, 8);  DECLW(W0j, 0, 9);  DECLW(W0k, 0, 10); DECLW(W0l, 0, 11);
    DECLW(W0m, 0, 12); DECLW(W0n, 0, 13); DECLW(W0o, 0, 14); DECLW(W0p, 0, 15);
    DECLW(W1a, 1, 0);  DECLW(W1b, 1, 1);  DECLW(W1c, 1, 2);  DECLW(W1d, 1, 3);
    DECLW(W1e, 1, 4);  DECLW(W1f, 1, 5);  DECLW(W1g, 1, 6);  DECLW(W1h, 1, 7);
    DECLW(W1i, 1, 8);  DECLW(W1j, 1, 9);  DECLW(W1k, 1, 10); DECLW(W1l, 1, 11);
    DECLW(W1m, 1, 12); DECLW(W1n, 1, 13); DECLW(W1o, 1, 14); DECLW(W1p, 1, 15);
    DECLW(W2a, 2, 0);  DECLW(W2b, 2, 1);  DECLW(W2c, 2, 2);  DECLW(W2d, 2, 3);
    DECLW(W2e, 2, 4);  DECLW(W2f, 2, 5);  DECLW(W2g, 2, 6);  DECLW(W2h, 2, 7);
    DECLW(W2i, 2, 8);  DECLW(W2j, 2, 9);  DECLW(W2k, 2, 10); DECLW(W2l, 2, 11);
    DECLW(W2m, 2, 12); DECLW(W2n, 2, 13);

    // ---- per-col constants
    float dd[4], dc[4], bb[4];
    #pragma unroll
    for (int tile = 0; tile < 4; tile++) {
        int col = w * 64 + tile * 16 + (l & 15);
        float s = 1.f / (1.f + __expf(-tau[col]));
        dd[tile] = s; dc[tile] = 1.f - s; bb[tile] = brv[col];
    }
    const int mr4 = (l >> 4) * 4;
    unsigned hpk[4][2] = {};

    __syncthreads();                          // h16 zeros + wlds ready

    for (int t = 0; t < NSTEP; ++t) {
        floatv4 xv0, xv1, xv2, xv3;
        LDXV(xv0, 0); LDXV(xv1, 1); LDXV(xv2, 2); LDXV(xv3, 3);

        f32x4 acc0 = {}, acc1 = {}, acc2 = {}, acc3 = {};
        KSTEP_V(0,  W0a, W1a, W2a);
        KSTEP_V(1,  W0b, W1b, W2b);
        KSTEP_V(2,  W0c, W1c, W2c);
        KSTEP_V(3,  W0d, W1d, W2d);
        KSTEP_V(4,  W0e, W1e, W2e);
        KSTEP_V(5,  W0f, W1f, W2f);
        KSTEP_V(6,  W0g, W1g, W2g);
        KSTEP_V(7,  W0h, W1h, W2h);
        KSTEP_V(8,  W0i, W1i, W2i);
        KSTEP_V(9,  W0j, W1j, W2j);
        KSTEP_V(10, W0k, W1k, W2k);
        KSTEP_V(11, W0l, W1l, W2l);
        KSTEP_V(12, W0m, W1m, W2m);
        KSTEP_V(13, W0n, W1n, W2n);
        KSTEP_L(14, W0o, W1o, 16);
        KSTEP_L(15, W0p, W1p, 17);
        __syncthreads();                      // all reads of h_t complete

        UPD(0, acc0, xv0);
        UPD(1, acc1, xv1);
        UPD(2, acc2, xv2);
        UPD(3, acc3, xv3);
        __syncthreads();                      // h_{t+1} visible to all waves
    }

    #pragma unroll
    for (int tile = 0; tile < 4; tile++)
        #pragma unroll
        for (int r = 0; r < 4; r++) {
            _Float16 hv;
            *(unsigned short*)&hv = (unsigned short)((hpk[tile][r >> 1] >> ((r & 1) * 16)) & 0xffff);
            int col = w * 64 + tile * 16 + (l & 15);
            hfinal[(size_t)(g * 16 + mr4 + r) * 512 + col] = (float)hv;
        }
}

// ---------------------------------------------------------------- launch
extern "C" void kernel_launch(void* const* d_in, const int* in_sizes, int n_in,
                              void* d_out, int out_size, void* d_ws, size_t ws_size,
                              hipStream_t stream) {
    const float* x   = (const float*)d_in[0];
    const float* Wi  = (const float*)d_in[1];
    const float* bi  = (const float*)d_in[2];
    const float* Wr  = (const float*)d_in[3];
    const float* br  = (const float*)d_in[4];
    const float* tau = (const float*)d_in[5];
    const float* Wo  = (const float*)d_in[6];
    const float* bo  = (const float*)d_in[7];

    float* out    = (float*)d_out;
    float* xin    = (float*)d_out;                       // reuse outs region for xin [S,B,H] fp32
    float* hfinal = (float*)d_out + (size_t)33554432;    // after B*S*DOUT

    // ws: hs fp16 [S,B,H] (64 MiB). Nothing else.
    unsigned short* hs = (unsigned short*)d_ws;

    hipLaunchKernelGGL(gemm_xin, dim3(512, 4), dim3(256), 0, stream, x, Wi, bi, xin);
    hipLaunchKernelGGL(scan_g, dim3(4), dim3(512), 0, stream, Wr, br, tau, xin, hs, hfinal);
    hipLaunchKernelGGL(gemm_out, dim3(512, 4), dim3(256), 0, stream, hs, Wo, bo, out);
}

// Round 13
// 6550.165 us; speedup vs baseline: 1.0745x; 1.0745x over previous
//
#include <hip/hip_runtime.h>
#include <hip/hip_bf16.h>
#include <hip/hip_fp16.h>

// LiquidLinear: xin = x@Wi^T + bi ; scan: h' = (1-sig(tau))h + sig(tau)tanh(xin_t + h@Wr^T + br)
// outs = hs@Wo^T + bo ; outputs = [outs (B,S,DOUT) fp32][h_final (B,H) fp32]
// B=64 S=1024 DIN=H=DOUT=512
//
// R13: design TO the 128-VGPR allocation point (R9-R12: every attempt to get
// >128 VGPRs produced 128 + scratch spills; 5.4-7.2ms). A 1024-thread block
// (16 waves) at 128 regs/wave owns 16x128x256B = 512KB of register file =
// exactly sizeof(Wr fp16). Per wave (32 cols): 24 weight frags in VGPR
// (96 regs, named vars) + 8 frags in LDS (8KB). Weights fully resident with
// NO allocator fight: need ~124 regs <= 128 cap. br folded into xin at GEMM1;
// dc=1-dd computed on the fly (saves regs). 4 blocks, exchange-free.

typedef _Float16 f16x8 __attribute__((ext_vector_type(8)));
typedef float f32x4 __attribute__((ext_vector_type(4)));
typedef float floatv4 __attribute__((ext_vector_type(4)));
typedef unsigned short ushort4v __attribute__((ext_vector_type(4)));
typedef unsigned int uint4v __attribute__((ext_vector_type(4)));

#define NSTEP 1024

__device__ __forceinline__ unsigned short f2h(float f) {
    _Float16 h = (_Float16)f;
    return *(unsigned short*)&h;
}
__device__ __forceinline__ float tanh_fast(float x) {
    float e = __expf(2.f * x);
    return 1.f - 2.f / (e + 1.f);
}

// ---------------------------------------------------------------- GEMM1: xin = x @ Wi^T + (bi+br)
__global__ __launch_bounds__(256) void gemm_xin(
    const float* __restrict__ X, const float* __restrict__ Wi,
    const float* __restrict__ bi, const float* __restrict__ brv,
    float* __restrict__ xin)
{
    __shared__ unsigned short As[128][40];
    __shared__ unsigned short Bs[128][40];
    const int bm = blockIdx.x, bn = blockIdx.y;
    const int tid = threadIdx.x, w = tid >> 6, l = tid & 63;
    const int wm = w >> 1, wn = w & 1;
    f32x4 acc[4][4] = {};

    for (int kt = 0; kt < 512; kt += 32) {
        __syncthreads();
        #pragma unroll
        for (int j = 0; j < 4; j++) {
            int q = tid + 256 * j;
            int row = q >> 3, c4 = (q & 7) * 4;
            floatv4 va = *(const floatv4*)&X[(size_t)(bm * 128 + row) * 512 + kt + c4];
            floatv4 vb = *(const floatv4*)&Wi[(size_t)(bn * 128 + row) * 512 + kt + c4];
            ushort4v pa, pb;
            #pragma unroll
            for (int e = 0; e < 4; e++) { pa[e] = f2h(va[e]); pb[e] = f2h(vb[e]); }
            *(ushort4v*)&As[row][c4] = pa;
            *(ushort4v*)&Bs[row][c4] = pb;
        }
        __syncthreads();
        f16x8 a[4], b[4];
        #pragma unroll
        for (int i = 0; i < 4; i++)
            a[i] = *(const f16x8*)&As[wm * 64 + i * 16 + (l & 15)][(l >> 4) * 8];
        #pragma unroll
        for (int i = 0; i < 4; i++)
            b[i] = *(const f16x8*)&Bs[wn * 64 + i * 16 + (l & 15)][(l >> 4) * 8];
        #pragma unroll
        for (int i = 0; i < 4; i++)
            #pragma unroll
            for (int j = 0; j < 4; j++)
                acc[i][j] = __builtin_amdgcn_mfma_f32_16x16x32_f16(a[i], b[j], acc[i][j], 0, 0, 0);
    }
    #pragma unroll
    for (int i = 0; i < 4; i++)
        #pragma unroll
        for (int j = 0; j < 4; j++)
            #pragma unroll
            for (int r = 0; r < 4; r++) {
                int m = bm * 128 + wm * 64 + i * 16 + (l >> 4) * 4 + r;
                int n = bn * 128 + wn * 64 + j * 16 + (l & 15);
                int bb = m >> 10, tt = m & 1023;
                xin[((size_t)tt * 64 + bb) * 512 + n] = acc[i][j][r] + bi[n] + brv[n];
            }
}

// ---------------------------------------------------------------- GEMM3: outs = hs @ Wo^T + bo
__global__ __launch_bounds__(256) void gemm_out(
    const unsigned short* __restrict__ hs, const float* __restrict__ Wo,
    const float* __restrict__ bo, float* __restrict__ out)
{
    __shared__ unsigned short As[128][40];
    __shared__ unsigned short Bs[128][40];
    const int bm = blockIdx.x, bn = blockIdx.y;
    const int tid = threadIdx.x, w = tid >> 6, l = tid & 63;
    const int wm = w >> 1, wn = w & 1;
    f32x4 acc[4][4] = {};

    for (int kt = 0; kt < 512; kt += 32) {
        __syncthreads();
        #pragma unroll
        for (int j = 0; j < 2; j++) {
            int q = tid + 256 * j;
            int row = q >> 2, c8 = (q & 3) * 8;
            int r = bm * 128 + row;
            int ra = (r & 1023) * 64 + (r >> 10);
            f16x8 v = *(const f16x8*)&hs[(size_t)ra * 512 + kt + c8];
            *(f16x8*)&As[row][c8] = v;
        }
        #pragma unroll
        for (int j = 0; j < 4; j++) {
            int q = tid + 256 * j;
            int row = q >> 3, c4 = (q & 7) * 4;
            floatv4 vb = *(const floatv4*)&Wo[(size_t)(bn * 128 + row) * 512 + kt + c4];
            ushort4v pb;
            #pragma unroll
            for (int e = 0; e < 4; e++) pb[e] = f2h(vb[e]);
            *(ushort4v*)&Bs[row][c4] = pb;
        }
        __syncthreads();
        f16x8 a[4], b[4];
        #pragma unroll
        for (int i = 0; i < 4; i++)
            a[i] = *(const f16x8*)&As[wm * 64 + i * 16 + (l & 15)][(l >> 4) * 8];
        #pragma unroll
        for (int i = 0; i < 4; i++)
            b[i] = *(const f16x8*)&Bs[wn * 64 + i * 16 + (l & 15)][(l >> 4) * 8];
        #pragma unroll
        for (int i = 0; i < 4; i++)
            #pragma unroll
            for (int j = 0; j < 4; j++)
                acc[i][j] = __builtin_amdgcn_mfma_f32_16x16x32_f16(a[i], b[j], acc[i][j], 0, 0, 0);
    }
    #pragma unroll
    for (int i = 0; i < 4; i++)
        #pragma unroll
        for (int j = 0; j < 4; j++)
            #pragma unroll
            for (int r = 0; r < 4; r++) {
                int m = bm * 128 + wm * 64 + i * 16 + (l >> 4) * 4 + r;
                int n = bn * 128 + wn * 64 + j * 16 + (l & 15);
                out[(size_t)m * 512 + n] = acc[i][j][r] + bo[n];
            }
}

// ---------------------------------------------------------------- scan (exchange-free, 16 waves)
// 4 blocks x 1024 threads. Block g owns batches [g*16,+16); wave w owns cols
// [w*32,+32) = tile0 (w*32) + tile1 (w*32+16). Weights: tile0 kt0-15 + tile1
// kt0-7 in 24 NAMED VGPR frags (96 regs); tile1 kt8-15 in LDS (8 chunks/wave).
// h: [16][512] fp16 LDS, XOR-swizzled (byte ^= (row&7)<<4).
#define LDW(DST, TILE, KT) do {                                                          \
    const float* p_ = &Wr[(size_t)(w * 32 + (TILE) * 16 + (l & 15)) * 512               \
                          + (KT) * 32 + (l >> 4) * 8];                                   \
    floatv4 u0_ = *(const floatv4*)p_;                                                   \
    floatv4 u1_ = *(const floatv4*)(p_ + 4);                                             \
    f16x8 f_;                                                                            \
    f_[0] = (_Float16)u0_[0]; f_[1] = (_Float16)u0_[1];                                  \
    f_[2] = (_Float16)u0_[2]; f_[3] = (_Float16)u0_[3];                                  \
    f_[4] = (_Float16)u1_[0]; f_[5] = (_Float16)u1_[1];                                  \
    f_[6] = (_Float16)u1_[2]; f_[7] = (_Float16)u1_[3];                                  \
    DST = f_;                                                                            \
} while (0)

#define DECLW(NAME, TILE, KT) f16x8 NAME; LDW(NAME, TILE, KT)

#define AH(KT) (*(const f16x8*)((const char*)h16 +                                       \
    ((((l & 15) * 1024) + (KT) * 64 + ((l >> 4) * 16)) ^ ((l & 7) << 4))))

#define BL(CH) (*(const f16x8*)&wlds[(w * 8 + (CH)) * 512 + l * 8])

#define MF(A, B, C) C = __builtin_amdgcn_mfma_f32_16x16x32_f16(A, B, C, 0, 0, 0)

#define KSTEP_VV(KT, B0, B1) do {                                                        \
    f16x8 ah_ = AH(KT);                                                                  \
    MF(ah_, B0, acc0); MF(ah_, B1, acc1);                                                \
} while (0)

#define KSTEP_VL(KT, B0) do {                                                            \
    f16x8 ah_ = AH(KT);                                                                  \
    MF(ah_, B0, acc0); MF(ah_, BL((KT) - 8), acc1);                                      \
} while (0)

#define LDXV(XV, TILE) do {                                                              \
    const float* q_ = &xin[((size_t)t * 64 + g * 16 + mr4) * 512                         \
                           + w * 32 + (TILE) * 16 + (l & 15)];                           \
    XV[0] = q_[0]; XV[1] = q_[512]; XV[2] = q_[1024]; XV[3] = q_[1536];                  \
} while (0)

#define UPD(TILE, ACC, XV, DD) do {                                                      \
    float dc_ = 1.f - (DD);                                                              \
    _Float16 h0_, h1_, h2_, h3_;                                                         \
    *(unsigned short*)&h0_ = (unsigned short)(hpk[TILE][0] & 0xffff);                    \
    *(unsigned short*)&h1_ = (unsigned short)(hpk[TILE][0] >> 16);                       \
    *(unsigned short*)&h2_ = (unsigned short)(hpk[TILE][1] & 0xffff);                    \
    *(unsigned short*)&h3_ = (unsigned short)(hpk[TILE][1] >> 16);                       \
    float n0_ = dc_ * (float)h0_ + (DD) * tanh_fast(ACC[0] + XV[0]);                     \
    float n1_ = dc_ * (float)h1_ + (DD) * tanh_fast(ACC[1] + XV[1]);                     \
    float n2_ = dc_ * (float)h2_ + (DD) * tanh_fast(ACC[2] + XV[2]);                     \
    float n3_ = dc_ * (float)h3_ + (DD) * tanh_fast(ACC[3] + XV[3]);                     \
    unsigned short q0_ = f2h(n0_), q1_ = f2h(n1_), q2_ = f2h(n2_), q3_ = f2h(n3_);       \
    hpk[TILE][0] = (unsigned)q0_ | ((unsigned)q1_ << 16);                                \
    hpk[TILE][1] = (unsigned)q2_ | ((unsigned)q3_ << 16);                                \
    int col_ = w * 32 + (TILE) * 16 + (l & 15);                                          \
    int b0_ = ((mr4 + 0) * 1024 + col_ * 2) ^ (((mr4 + 0) & 7) << 4);                    \
    int b1_ = ((mr4 + 1) * 1024 + col_ * 2) ^ (((mr4 + 1) & 7) << 4);                    \
    int b2_ = ((mr4 + 2) * 1024 + col_ * 2) ^ (((mr4 + 2) & 7) << 4);                    \
    int b3_ = ((mr4 + 3) * 1024 + col_ * 2) ^ (((mr4 + 3) & 7) << 4);                    \
    *(unsigned short*)((char*)h16 + b0_) = q0_;                                          \
    *(unsigned short*)((char*)h16 + b1_) = q1_;                                          \
    *(unsigned short*)((char*)h16 + b2_) = q2_;                                          \
    *(unsigned short*)((char*)h16 + b3_) = q3_;                                          \
    size_t hr_ = ((size_t)t * 64 + g * 16 + mr4) * 512 + col_;                           \
    hs[hr_] = q0_; hs[hr_ + 512] = q1_; hs[hr_ + 1024] = q2_; hs[hr_ + 1536] = q3_;      \
} while (0)

__global__ __launch_bounds__(1024, 1) void scan_g(
    const float* __restrict__ Wr, const float* __restrict__ tau,
    const float* __restrict__ xin, unsigned short* __restrict__ hs,
    float* __restrict__ hfinal)
{
    const int g = blockIdx.x;
    const int tid = threadIdx.x, w = tid >> 6, l = tid & 63;

    __shared__ unsigned short wlds[65536];   // 128KB: 16 waves x 8 chunks x 512 ushort
    __shared__ unsigned short h16[8192];     // 16KB: h fp16 [16][512], XOR-swizzled

    if (tid < 1024) ((uint4v*)h16)[tid] = uint4v{0, 0, 0, 0};

    // ---- LDS-resident weights: tile1 kt 8..15 -> chunks 0..7 of wave w
    #pragma unroll
    for (int kt = 8; kt < 16; kt++) {
        const float* p = &Wr[(size_t)(w * 32 + 16 + (l & 15)) * 512 + kt * 32 + (l >> 4) * 8];
        f16x8 f;
        #pragma unroll
        for (int e = 0; e < 8; e++) f[e] = (_Float16)p[e];
        *(f16x8*)&wlds[(w * 8 + (kt - 8)) * 512 + l * 8] = f;
    }

    // ---- 24 named VGPR weight fragments (96 regs)
    DECLW(W0a, 0, 0);  DECLW(W0b, 0, 1);  DECLW(W0c, 0, 2);  DECLW(W0d, 0, 3);
    DECLW(W0e, 0, 4);  DECLW(W0f, 0, 5);  DECLW(W0g, 0, 6);  DECLW(W0h, 0, 7);
    DECLW(W0i, 0, 8);  DECLW(W0j, 0, 9);  DECLW(W0k, 0, 10); DECLW(W0l, 0, 11);
    DECLW(W0m, 0, 12); DECLW(W0n, 0, 13); DECLW(W0o, 0, 14); DECLW(W0p, 0, 15);
    DECLW(W1a, 1, 0);  DECLW(W1b, 1, 1);  DECLW(W1c, 1, 2);  DECLW(W1d, 1, 3);
    DECLW(W1e, 1, 4);  DECLW(W1f, 1, 5);  DECLW(W1g, 1, 6);  DECLW(W1h, 1, 7);

    // ---- per-col decay (2 tiles); 1-d computed on the fly
    float dd0, dd1;
    {
        int c0 = w * 32 + (l & 15), c1 = c0 + 16;
        dd0 = 1.f / (1.f + __expf(-tau[c0]));
        dd1 = 1.f / (1.f + __expf(-tau[c1]));
    }
    const int mr4 = (l >> 4) * 4;
    unsigned hpk[2][2] = {};

    __syncthreads();                          // h16 zeros + wlds ready

    for (int t = 0; t < NSTEP; ++t) {
        floatv4 xv0, xv1;
        LDXV(xv0, 0); LDXV(xv1, 1);

        f32x4 acc0 = {}, acc1 = {};
        KSTEP_VV(0,  W0a, W1a);
        KSTEP_VV(1,  W0b, W1b);
        KSTEP_VV(2,  W0c, W1c);
        KSTEP_VV(3,  W0d, W1d);
        KSTEP_VV(4,  W0e, W1e);
        KSTEP_VV(5,  W0f, W1f);
        KSTEP_VV(6,  W0g, W1g);
        KSTEP_VV(7,  W0h, W1h);
        KSTEP_VL(8,  W0i);
        KSTEP_VL(9,  W0j);
        KSTEP_VL(10, W0k);
        KSTEP_VL(11, W0l);
        KSTEP_VL(12, W0m);
        KSTEP_VL(13, W0n);
        KSTEP_VL(14, W0o);
        KSTEP_VL(15, W0p);
        __syncthreads();                      // all reads of h_t complete

        UPD(0, acc0, xv0, dd0);
        UPD(1, acc1, xv1, dd1);
        __syncthreads();                      // h_{t+1} visible to all waves
    }

    #pragma unroll
    for (int tile = 0; tile < 2; tile++)
        #pragma unroll
        for (int r = 0; r < 4; r++) {
            _Float16 hv;
            *(unsigned short*)&hv = (unsigned short)((hpk[tile][r >> 1] >> ((r & 1) * 16)) & 0xffff);
            int col = w * 32 + tile * 16 + (l & 15);
            hfinal[(size_t)(g * 16 + mr4 + r) * 512 + col] = (float)hv;
        }
}

// ---------------------------------------------------------------- launch
extern "C" void kernel_launch(void* const* d_in, const int* in_sizes, int n_in,
                              void* d_out, int out_size, void* d_ws, size_t ws_size,
                              hipStream_t stream) {
    const float* x   = (const float*)d_in[0];
    const float* Wi  = (const float*)d_in[1];
    const float* bi  = (const float*)d_in[2];
    const float* Wr  = (const float*)d_in[3];
    const float* br  = (const float*)d_in[4];
    const float* tau = (const float*)d_in[5];
    const float* Wo  = (const float*)d_in[6];
    const float* bo  = (const float*)d_in[7];

    float* out    = (float*)d_out;
    float* xin    = (float*)d_out;                       // reuse outs region for xin [S,B,H] fp32
    float* hfinal = (float*)d_out + (size_t)33554432;    // after B*S*DOUT

    // ws: hs fp16 [S,B,H] (64 MiB). Nothing else.
    unsigned short* hs = (unsigned short*)d_ws;

    hipLaunchKernelGGL(gemm_xin, dim3(512, 4), dim3(256), 0, stream, x, Wi, bi, br, xin);
    hipLaunchKernelGGL(scan_g, dim3(4), dim3(1024), 0, stream, Wr, tau, xin, hs, hfinal);
    hipLaunchKernelGGL(gemm_out, dim3(512, 4), dim3(256), 0, stream, hs, Wo, bo, out);
}

// Round 14
// 6532.535 us; speedup vs baseline: 1.0774x; 1.0027x over previous
//
#include <hip/hip_runtime.h>
#include <hip/hip_bf16.h>
#include <hip/hip_fp16.h>

// LiquidLinear: xin = x@Wi^T + bi ; scan: h' = (1-sig(tau))h + sig(tau)tanh(xin_t + h@Wr^T + br)
// outs = hs@Wo^T + bo ; outputs = [outs (B,S,DOUT) fp32][h_final (B,H) fp32]
// B=64 S=1024 DIN=H=DOUT=512
//
// R14: kill the weight-load SINKING (R11-R13 root cause: compiler legally
// re-loads const Wr from L2 + re-runs fp32->fp16 cvts EVERY step -> ~1.5MB/step/CU
// L2-BW-bound = 5.4-6.3us/step; VGPR_Count 64-128 because pressure never
// materializes at RA).
//  (1) Wr pre-converted to fp16 ONCE into workspace (cvt kernel).
//  (2) every named VGPR weight frag pinned with asm volatile(""::"+v") -- opaque
//      output cannot be rematerialized-by-reload; value must stay live.
//  (3) R13 shape: 4 blocks x 1024 thr (16 waves), wave owns 32 cols; 24 pinned
//      frags (96 regs) + 8 LDS chunks/wave (128KB) + h16 16KB; waves_per_eu(4,4)
//      -> RA cap 128 >= ~126 pressure.

typedef _Float16 f16x8 __attribute__((ext_vector_type(8)));
typedef float f32x4 __attribute__((ext_vector_type(4)));
typedef float floatv4 __attribute__((ext_vector_type(4)));
typedef unsigned short ushort4v __attribute__((ext_vector_type(4)));
typedef unsigned int uint4v __attribute__((ext_vector_type(4)));

#define NSTEP 1024

__device__ __forceinline__ unsigned short f2h(float f) {
    _Float16 h = (_Float16)f;
    return *(unsigned short*)&h;
}
__device__ __forceinline__ float tanh_fast(float x) {
    float e = __expf(2.f * x);
    return 1.f - 2.f / (e + 1.f);
}

// ---------------------------------------------------------------- cvt: Wr fp32 -> fp16
__global__ __launch_bounds__(256) void cvt_wr(const float* __restrict__ Wr,
                                              unsigned short* __restrict__ Wr16) {
    int i = (blockIdx.x * 256 + threadIdx.x) * 4;
    floatv4 v = *(const floatv4*)&Wr[i];
    ushort4v o;
    o[0] = f2h(v[0]); o[1] = f2h(v[1]); o[2] = f2h(v[2]); o[3] = f2h(v[3]);
    *(ushort4v*)&Wr16[i] = o;
}

// ---------------------------------------------------------------- GEMM1: xin = x @ Wi^T + (bi+br)
__global__ __launch_bounds__(256) void gemm_xin(
    const float* __restrict__ X, const float* __restrict__ Wi,
    const float* __restrict__ bi, const float* __restrict__ brv,
    float* __restrict__ xin)
{
    __shared__ unsigned short As[128][40];
    __shared__ unsigned short Bs[128][40];
    const int bm = blockIdx.x, bn = blockIdx.y;
    const int tid = threadIdx.x, w = tid >> 6, l = tid & 63;
    const int wm = w >> 1, wn = w & 1;
    f32x4 acc[4][4] = {};

    for (int kt = 0; kt < 512; kt += 32) {
        __syncthreads();
        #pragma unroll
        for (int j = 0; j < 4; j++) {
            int q = tid + 256 * j;
            int row = q >> 3, c4 = (q & 7) * 4;
            floatv4 va = *(const floatv4*)&X[(size_t)(bm * 128 + row) * 512 + kt + c4];
            floatv4 vb = *(const floatv4*)&Wi[(size_t)(bn * 128 + row) * 512 + kt + c4];
            ushort4v pa, pb;
            #pragma unroll
            for (int e = 0; e < 4; e++) { pa[e] = f2h(va[e]); pb[e] = f2h(vb[e]); }
            *(ushort4v*)&As[row][c4] = pa;
            *(ushort4v*)&Bs[row][c4] = pb;
        }
        __syncthreads();
        f16x8 a[4], b[4];
        #pragma unroll
        for (int i = 0; i < 4; i++)
            a[i] = *(const f16x8*)&As[wm * 64 + i * 16 + (l & 15)][(l >> 4) * 8];
        #pragma unroll
        for (int i = 0; i < 4; i++)
            b[i] = *(const f16x8*)&Bs[wn * 64 + i * 16 + (l & 15)][(l >> 4) * 8];
        #pragma unroll
        for (int i = 0; i < 4; i++)
            #pragma unroll
            for (int j = 0; j < 4; j++)
                acc[i][j] = __builtin_amdgcn_mfma_f32_16x16x32_f16(a[i], b[j], acc[i][j], 0, 0, 0);
    }
    #pragma unroll
    for (int i = 0; i < 4; i++)
        #pragma unroll
        for (int j = 0; j < 4; j++)
            #pragma unroll
            for (int r = 0; r < 4; r++) {
                int m = bm * 128 + wm * 64 + i * 16 + (l >> 4) * 4 + r;
                int n = bn * 128 + wn * 64 + j * 16 + (l & 15);
                int bb = m >> 10, tt = m & 1023;
                xin[((size_t)tt * 64 + bb) * 512 + n] = acc[i][j][r] + bi[n] + brv[n];
            }
}

// ---------------------------------------------------------------- GEMM3: outs = hs @ Wo^T + bo
__global__ __launch_bounds__(256) void gemm_out(
    const unsigned short* __restrict__ hs, const float* __restrict__ Wo,
    const float* __restrict__ bo, float* __restrict__ out)
{
    __shared__ unsigned short As[128][40];
    __shared__ unsigned short Bs[128][40];
    const int bm = blockIdx.x, bn = blockIdx.y;
    const int tid = threadIdx.x, w = tid >> 6, l = tid & 63;
    const int wm = w >> 1, wn = w & 1;
    f32x4 acc[4][4] = {};

    for (int kt = 0; kt < 512; kt += 32) {
        __syncthreads();
        #pragma unroll
        for (int j = 0; j < 2; j++) {
            int q = tid + 256 * j;
            int row = q >> 2, c8 = (q & 3) * 8;
            int r = bm * 128 + row;
            int ra = (r & 1023) * 64 + (r >> 10);
            f16x8 v = *(const f16x8*)&hs[(size_t)ra * 512 + kt + c8];
            *(f16x8*)&As[row][c8] = v;
        }
        #pragma unroll
        for (int j = 0; j < 4; j++) {
            int q = tid + 256 * j;
            int row = q >> 3, c4 = (q & 7) * 4;
            floatv4 vb = *(const floatv4*)&Wo[(size_t)(bn * 128 + row) * 512 + kt + c4];
            ushort4v pb;
            #pragma unroll
            for (int e = 0; e < 4; e++) pb[e] = f2h(vb[e]);
            *(ushort4v*)&Bs[row][c4] = pb;
        }
        __syncthreads();
        f16x8 a[4], b[4];
        #pragma unroll
        for (int i = 0; i < 4; i++)
            a[i] = *(const f16x8*)&As[wm * 64 + i * 16 + (l & 15)][(l >> 4) * 8];
        #pragma unroll
        for (int i = 0; i < 4; i++)
            b[i] = *(const f16x8*)&Bs[wn * 64 + i * 16 + (l & 15)][(l >> 4) * 8];
        #pragma unroll
        for (int i = 0; i < 4; i++)
            #pragma unroll
            for (int j = 0; j < 4; j++)
                acc[i][j] = __builtin_amdgcn_mfma_f32_16x16x32_f16(a[i], b[j], acc[i][j], 0, 0, 0);
    }
    #pragma unroll
    for (int i = 0; i < 4; i++)
        #pragma unroll
        for (int j = 0; j < 4; j++)
            #pragma unroll
            for (int r = 0; r < 4; r++) {
                int m = bm * 128 + wm * 64 + i * 16 + (l >> 4) * 4 + r;
                int n = bn * 128 + wn * 64 + j * 16 + (l & 15);
                out[(size_t)m * 512 + n] = acc[i][j][r] + bo[n];
            }
}

// ---------------------------------------------------------------- scan (exchange-free, pinned frags)
// 4 blocks x 1024 threads. Block g owns batches [g*16,+16); wave w owns cols
// [w*32,+32): tile0 kt0-15 + tile1 kt0-7 in 24 PINNED VGPR frags (96 regs);
// tile1 kt8-15 in LDS (8 chunks/wave, 128KB). h: [16][512] fp16, XOR-swizzled.
#define PIN(X) asm volatile("" : "+v"(X))

#define DECLW(NAME, TILE, KT)                                                            \
    f16x8 NAME = *(const f16x8*)&Wr16[(size_t)(w * 32 + (TILE) * 16 + (l & 15)) * 512    \
                                      + (KT) * 32 + (l >> 4) * 8];                       \
    PIN(NAME)

#define AH(KT) (*(const f16x8*)((const char*)h16 +                                       \
    ((((l & 15) * 1024) + (KT) * 64 + ((l >> 4) * 16)) ^ ((l & 7) << 4))))

#define BL(CH) (*(const f16x8*)&wlds[(w * 8 + (CH)) * 512 + l * 8])

#define MF(A, B, C) C = __builtin_amdgcn_mfma_f32_16x16x32_f16(A, B, C, 0, 0, 0)

#define KSTEP_VV(KT, B0, B1) do {                                                        \
    f16x8 ah_ = AH(KT);                                                                  \
    MF(ah_, B0, acc0); MF(ah_, B1, acc1);                                                \
} while (0)

#define KSTEP_VL(KT, B0) do {                                                            \
    f16x8 ah_ = AH(KT);                                                                  \
    MF(ah_, B0, acc0); MF(ah_, BL((KT) - 8), acc1);                                      \
} while (0)

#define LDXV(XV, TILE) do {                                                              \
    const float* q_ = &xin[((size_t)t * 64 + g * 16 + mr4) * 512                         \
                           + w * 32 + (TILE) * 16 + (l & 15)];                           \
    XV[0] = q_[0]; XV[1] = q_[512]; XV[2] = q_[1024]; XV[3] = q_[1536];                  \
} while (0)

#define UPD(TILE, ACC, XV, DD) do {                                                      \
    float dc_ = 1.f - (DD);                                                              \
    _Float16 h0_, h1_, h2_, h3_;                                                         \
    *(unsigned short*)&h0_ = (unsigned short)(hpk[TILE][0] & 0xffff);                    \
    *(unsigned short*)&h1_ = (unsigned short)(hpk[TILE][0] >> 16);                       \
    *(unsigned short*)&h2_ = (unsigned short)(hpk[TILE][1] & 0xffff);                    \
    *(unsigned short*)&h3_ = (unsigned short)(hpk[TILE][1] >> 16);                       \
    float n0_ = dc_ * (float)h0_ + (DD) * tanh_fast(ACC[0] + XV[0]);                     \
    float n1_ = dc_ * (float)h1_ + (DD) * tanh_fast(ACC[1] + XV[1]);                     \
    float n2_ = dc_ * (float)h2_ + (DD) * tanh_fast(ACC[2] + XV[2]);                     \
    float n3_ = dc_ * (float)h3_ + (DD) * tanh_fast(ACC[3] + XV[3]);                     \
    unsigned short q0_ = f2h(n0_), q1_ = f2h(n1_), q2_ = f2h(n2_), q3_ = f2h(n3_);       \
    hpk[TILE][0] = (unsigned)q0_ | ((unsigned)q1_ << 16);                                \
    hpk[TILE][1] = (unsigned)q2_ | ((unsigned)q3_ << 16);                                \
    int col_ = w * 32 + (TILE) * 16 + (l & 15);                                          \
    int b0_ = ((mr4 + 0) * 1024 + col_ * 2) ^ (((mr4 + 0) & 7) << 4);                    \
    int b1_ = ((mr4 + 1) * 1024 + col_ * 2) ^ (((mr4 + 1) & 7) << 4);                    \
    int b2_ = ((mr4 + 2) * 1024 + col_ * 2) ^ (((mr4 + 2) & 7) << 4);                    \
    int b3_ = ((mr4 + 3) * 1024 + col_ * 2) ^ (((mr4 + 3) & 7) << 4);                    \
    *(unsigned short*)((char*)h16 + b0_) = q0_;                                          \
    *(unsigned short*)((char*)h16 + b1_) = q1_;                                          \
    *(unsigned short*)((char*)h16 + b2_) = q2_;                                          \
    *(unsigned short*)((char*)h16 + b3_) = q3_;                                          \
    size_t hr_ = ((size_t)t * 64 + g * 16 + mr4) * 512 + col_;                           \
    hs[hr_] = q0_; hs[hr_ + 512] = q1_; hs[hr_ + 1024] = q2_; hs[hr_ + 1536] = q3_;      \
} while (0)

__global__ __attribute__((amdgpu_flat_work_group_size(1024, 1024), amdgpu_waves_per_eu(4, 4)))
void scan_g(
    const unsigned short* __restrict__ Wr16, const float* __restrict__ tau,
    const float* __restrict__ xin, unsigned short* __restrict__ hs,
    float* __restrict__ hfinal)
{
    const int g = blockIdx.x;
    const int tid = threadIdx.x, w = tid >> 6, l = tid & 63;

    __shared__ unsigned short wlds[65536];   // 128KB: 16 waves x 8 chunks x 512 ushort
    __shared__ unsigned short h16[8192];     // 16KB: h fp16 [16][512], XOR-swizzled

    ((uint4v*)h16)[tid] = uint4v{0, 0, 0, 0};

    // ---- LDS-resident weights: tile1 kt 8..15 -> chunks 0..7 of wave w
    #pragma unroll
    for (int kt = 8; kt < 16; kt++) {
        f16x8 f = *(const f16x8*)&Wr16[(size_t)(w * 32 + 16 + (l & 15)) * 512
                                       + kt * 32 + (l >> 4) * 8];
        *(f16x8*)&wlds[(w * 8 + (kt - 8)) * 512 + l * 8] = f;
    }

    // ---- 24 named+PINNED VGPR weight fragments (96 regs; loads cannot sink)
    DECLW(W0a, 0, 0);  DECLW(W0b, 0, 1);  DECLW(W0c, 0, 2);  DECLW(W0d, 0, 3);
    DECLW(W0e, 0, 4);  DECLW(W0f, 0, 5);  DECLW(W0g, 0, 6);  DECLW(W0h, 0, 7);
    DECLW(W0i, 0, 8);  DECLW(W0j, 0, 9);  DECLW(W0k, 0, 10); DECLW(W0l, 0, 11);
    DECLW(W0m, 0, 12); DECLW(W0n, 0, 13); DECLW(W0o, 0, 14); DECLW(W0p, 0, 15);
    DECLW(W1a, 1, 0);  DECLW(W1b, 1, 1);  DECLW(W1c, 1, 2);  DECLW(W1d, 1, 3);
    DECLW(W1e, 1, 4);  DECLW(W1f, 1, 5);  DECLW(W1g, 1, 6);  DECLW(W1h, 1, 7);

    // ---- per-col decay; 1-d computed on the fly
    float dd0, dd1;
    {
        int c0 = w * 32 + (l & 15), c1 = c0 + 16;
        dd0 = 1.f / (1.f + __expf(-tau[c0]));
        dd1 = 1.f / (1.f + __expf(-tau[c1]));
    }
    const int mr4 = (l >> 4) * 4;
    unsigned hpk[2][2] = {};

    __syncthreads();                          // h16 zeros + wlds ready

    for (int t = 0; t < NSTEP; ++t) {
        floatv4 xv0, xv1;
        LDXV(xv0, 0); LDXV(xv1, 1);

        f32x4 acc0 = {}, acc1 = {};
        KSTEP_VV(0,  W0a, W1a);
        KSTEP_VV(1,  W0b, W1b);
        KSTEP_VV(2,  W0c, W1c);
        KSTEP_VV(3,  W0d, W1d);
        KSTEP_VV(4,  W0e, W1e);
        KSTEP_VV(5,  W0f, W1f);
        KSTEP_VV(6,  W0g, W1g);
        KSTEP_VV(7,  W0h, W1h);
        KSTEP_VL(8,  W0i);
        KSTEP_VL(9,  W0j);
        KSTEP_VL(10, W0k);
        KSTEP_VL(11, W0l);
        KSTEP_VL(12, W0m);
        KSTEP_VL(13, W0n);
        KSTEP_VL(14, W0o);
        KSTEP_VL(15, W0p);
        __syncthreads();                      // all reads of h_t complete

        UPD(0, acc0, xv0, dd0);
        UPD(1, acc1, xv1, dd1);
        __syncthreads();                      // h_{t+1} visible to all waves
    }

    #pragma unroll
    for (int tile = 0; tile < 2; tile++)
        #pragma unroll
        for (int r = 0; r < 4; r++) {
            _Float16 hv;
            *(unsigned short*)&hv = (unsigned short)((hpk[tile][r >> 1] >> ((r & 1) * 16)) & 0xffff);
            int col = w * 32 + tile * 16 + (l & 15);
            hfinal[(size_t)(g * 16 + mr4 + r) * 512 + col] = (float)hv;
        }
}

// ---------------------------------------------------------------- launch
extern "C" void kernel_launch(void* const* d_in, const int* in_sizes, int n_in,
                              void* d_out, int out_size, void* d_ws, size_t ws_size,
                              hipStream_t stream) {
    const float* x   = (const float*)d_in[0];
    const float* Wi  = (const float*)d_in[1];
    const float* bi  = (const float*)d_in[2];
    const float* Wr  = (const float*)d_in[3];
    const float* br  = (const float*)d_in[4];
    const float* tau = (const float*)d_in[5];
    const float* Wo  = (const float*)d_in[6];
    const float* bo  = (const float*)d_in[7];

    float* out    = (float*)d_out;
    float* xin    = (float*)d_out;                       // reuse outs region for xin [S,B,H] fp32
    float* hfinal = (float*)d_out + (size_t)33554432;    // after B*S*DOUT

    // ws: hs fp16 [S,B,H] (64 MiB) | Wr16 fp16 (512 KiB)
    unsigned short* hs   = (unsigned short*)d_ws;
    unsigned short* Wr16 = (unsigned short*)((char*)d_ws + (size_t)67108864);

    hipLaunchKernelGGL(cvt_wr, dim3(256), dim3(256), 0, stream, Wr, Wr16);
    hipLaunchKernelGGL(gemm_xin, dim3(512, 4), dim3(256), 0, stream, x, Wi, bi, br, xin);
    hipLaunchKernelGGL(scan_g, dim3(4), dim3(1024), 0, stream, Wr16, tau, xin, hs, hfinal);
    hipLaunchKernelGGL(gemm_out, dim3(512, 4), dim3(256), 0, stream, hs, Wo, bo, out);
}